// Round 1
// baseline (2141.996 us; speedup 1.0000x reference)
//
#include <hip/hip_runtime.h>
#include <hip/hip_bf16.h>
#include <cstdint>

// Problem constants
// B=8, S=16, N=1024, F=16, H=128, E=32768, L=4, BN=8192
#define EPS 1e-5f

__device__ __forceinline__ float sigm(float x) { return 1.f / (1.f + expf(-x)); }

// ---------------- edge attention: ew[e] = edge_weights[e] * sigmoid(relu(ef*w1+b1)@w2 + b2)
__global__ __launch_bounds__(256) void edge_att(const float* __restrict__ ef,
                                                const float* __restrict__ we1,
                                                const float* __restrict__ be1,
                                                const float* __restrict__ we2,
                                                const float* __restrict__ be2,
                                                const float* __restrict__ ewin,
                                                float* __restrict__ ew) {
    int e = blockIdx.x * blockDim.x + threadIdx.x;
    if (e >= 32768) return;
    float x = ef[e];
    float acc = 0.f;
    for (int h = 0; h < 128; ++h) {
        float v = fmaxf(x * we1[h] + be1[h], 0.f);
        acc += v * we2[h];
    }
    float att = sigm(acc + be2[0]);
    ew[e] = ewin[e] * att;
}

__global__ __launch_bounds__(256) void deg_init(float* __restrict__ deg) {
    int i = blockIdx.x * blockDim.x + threadIdx.x;
    if (i < 8192) deg[i] = 1.0f;   // self-loop weight
}
__global__ __launch_bounds__(256) void deg_acc(const int* __restrict__ dst,
                                               const float* __restrict__ ew,
                                               float* __restrict__ deg) {
    int e = blockIdx.x * blockDim.x + threadIdx.x;
    if (e < 32768) atomicAdd(&deg[dst[e]], ew[e]);
}
__global__ __launch_bounds__(256) void make_dis(float* __restrict__ deg) {
    int i = blockIdx.x * blockDim.x + threadIdx.x;
    if (i < 8192) { float d = deg[i]; deg[i] = (d > 0.f) ? rsqrtf(d) : 0.f; }
}
// Dense adjacency A[dst][src] += dis[src]*ew*dis[dst]
__global__ __launch_bounds__(256) void scatterA(const int* __restrict__ src,
                                                const int* __restrict__ dst,
                                                const float* __restrict__ ew,
                                                const float* __restrict__ dis,
                                                float* __restrict__ A) {
    int e = blockIdx.x * blockDim.x + threadIdx.x;
    if (e >= 32768) return;
    int s = src[e], d = dst[e];
    float nrm = dis[s] * ew[e] * dis[d];
    atomicAdd(&A[d * 1024 + s], nrm);
}

// ---------------- input projection + LayerNorm + ReLU, scattered directly into hcur[t][bn][h]
// Only rows k=t+b in [0,23) of xf are ever used -> grid over 23552 rows.
__global__ __launch_bounds__(128) void in_proj_ln(const float* __restrict__ x,
                                                  const float* __restrict__ w,
                                                  const float* __restrict__ bias,
                                                  const float* __restrict__ g,
                                                  const float* __restrict__ be,
                                                  float* __restrict__ hcur) {
    int r = blockIdx.x;            // 0..23551  (= k*1024 + n)
    int h = threadIdx.x;           // 0..127
    int k = r >> 10, n = r & 1023;
    __shared__ float xs[16];
    __shared__ float red[128];
    if (h < 16) xs[h] = x[(int64_t)r * 16 + h];
    __syncthreads();
    float acc = bias[h];
#pragma unroll
    for (int f = 0; f < 16; ++f) acc += xs[f] * w[f * 128 + h];
    red[h] = acc; __syncthreads();
    for (int off = 64; off; off >>= 1) { if (h < off) red[h] += red[h + off]; __syncthreads(); }
    float mu = red[0] * (1.f / 128.f); __syncthreads();
    float d = acc - mu; red[h] = d * d; __syncthreads();
    for (int off = 64; off; off >>= 1) { if (h < off) red[h] += red[h + off]; __syncthreads(); }
    float var = red[0] * (1.f / 128.f);
    float v = fmaxf(d * rsqrtf(var + EPS) * g[h] + be[h], 0.f);
#pragma unroll
    for (int b = 0; b < 8; ++b) {
        int t = k - b;
        if (t >= 0 && t < 16)
            hcur[((int64_t)t * 8192 + b * 1024 + n) * 128 + h] = v;
    }
}

// ---------------- generic fp32 tiled GEMM: C = A0@B0 (+ A1@B1) (+ bias), batched by blockIdx.z
// BM=BN=64, BK=16, 256 threads, 4x4 microtile. All dims assumed multiples of tile sizes.
template <bool DUAL, bool BIAS>
__global__ __launch_bounds__(256) void gemm_f32(const float* __restrict__ A0,
                                                const float* __restrict__ A1,
                                                const float* __restrict__ B0,
                                                const float* __restrict__ B1,
                                                const float* __restrict__ bias,
                                                float* __restrict__ C,
                                                int M, int N, int K,
                                                int lda, int ldb, int ldc,
                                                int64_t bsA, int64_t bsB, int64_t bsC) {
    __shared__ float As[16][68];
    __shared__ float Bs[16][68];
    const int bz = blockIdx.z;
    const int row0 = blockIdx.x * 64;
    const int col0 = blockIdx.y * 64;
    const int tid = threadIdx.x;
    const int tx = tid & 15;
    const int ty = tid >> 4;
    const int kA = (tid * 4) & 15;
    const int mA = (tid * 4) >> 4;
    const int cB = (tid * 4) & 63;
    const int kB = (tid * 4) >> 6;

    float acc[4][4] = {};
    const int nsrc = DUAL ? 2 : 1;
    for (int s = 0; s < nsrc; ++s) {
        const float* A = (s == 0 ? A0 : A1) + bz * bsA;
        const float* B = (s == 0 ? B0 : B1) + bz * bsB;
        for (int k0 = 0; k0 < K; k0 += 16) {
            float4 av = *(const float4*)(A + (int64_t)(row0 + mA) * lda + k0 + kA);
            float4 bv = *(const float4*)(B + (int64_t)(k0 + kB) * ldb + col0 + cB);
            __syncthreads();
            As[kA + 0][mA] = av.x; As[kA + 1][mA] = av.y;
            As[kA + 2][mA] = av.z; As[kA + 3][mA] = av.w;
            *(float4*)&Bs[kB][cB] = bv;
            __syncthreads();
#pragma unroll
            for (int k = 0; k < 16; ++k) {
                float4 a4 = *(const float4*)&As[k][ty * 4];
                float4 b4 = *(const float4*)&Bs[k][tx * 4];
                float a[4] = {a4.x, a4.y, a4.z, a4.w};
                float b[4] = {b4.x, b4.y, b4.z, b4.w};
#pragma unroll
                for (int i = 0; i < 4; ++i)
#pragma unroll
                    for (int j = 0; j < 4; ++j) acc[i][j] += a[i] * b[j];
            }
        }
    }
    float* Cp = C + bz * bsC;
#pragma unroll
    for (int i = 0; i < 4; ++i) {
        int r = row0 + ty * 4 + i;
        float4 v;
        float* vp = (float*)&v;
#pragma unroll
        for (int j = 0; j < 4; ++j) {
            float t = acc[i][j];
            if (BIAS) t += bias[col0 + tx * 4 + j];
            vp[j] = t;
        }
        *(float4*)(Cp + (int64_t)r * ldc + col0 + tx * 4) = v;
    }
}

// ---------------- GCN combine: h = relu((sl*hw + Apart + b)*bn_scale + bn_b) + h
__global__ __launch_bounds__(256) void gcn_combine(const float* __restrict__ hw,
                                                   const float* __restrict__ Apart,
                                                   const float* __restrict__ dis,
                                                   const float* __restrict__ gcnb,
                                                   const float* __restrict__ bng,
                                                   const float* __restrict__ bnb,
                                                   float* __restrict__ hcur) {
    int64_t i = (int64_t)blockIdx.x * blockDim.x + threadIdx.x;  // 16*8192*128
    int h = (int)(i & 127);
    int64_t rt = i >> 7;
    int bn = (int)(rt & 8191);
    int t = (int)(rt >> 13);
    float sl = dis[bn] * dis[bn];
    float m = sl * hw[i] + gcnb[h];
    if (bn < 1024) m += Apart[((int64_t)t * 1024 + bn) * 128 + h];
    float scale = bng[h] * rsqrtf(1.f + EPS);
    float v = fmaxf(m * scale + bnb[h], 0.f) + hcur[i];
    hcur[i] = v;
}

// ---------------- LSTM helpers
__global__ __launch_bounds__(256) void transpose_512x128(const float* __restrict__ w,
                                                         float* __restrict__ wt) {
    int i = blockIdx.x * blockDim.x + threadIdx.x;  // 2*512*128
    if (i >= 2 * 512 * 128) return;
    int l = i / (512 * 128);
    int rem = i - l * 512 * 128;
    int j = rem / 128, k = rem - j * 128;
    wt[l * 65536 + k * 512 + j] = w[i];
}
__global__ __launch_bounds__(256) void bias_sum(const float* __restrict__ bih,
                                                const float* __restrict__ bhh,
                                                float* __restrict__ bs) {
    int i = blockIdx.x * blockDim.x + threadIdx.x;
    if (i < 1024) bs[i] = bih[i] + bhh[i];
}
__global__ __launch_bounds__(256) void lstm_cell(const float* __restrict__ gates,
                                                 float* __restrict__ hstate,
                                                 float* __restrict__ cstate,
                                                 float* __restrict__ yout) {
    int i = blockIdx.x * blockDim.x + threadIdx.x;  // 8192*128
    int h = i & 127;
    int r = i >> 7;
    const float* g = gates + (int64_t)r * 512;
    float ig = sigm(g[h]);
    float fg = sigm(g[128 + h]);
    float gg = tanhf(g[256 + h]);
    float og = sigm(g[384 + h]);
    float c = fg * cstate[i] + ig * gg;
    float hn = og * tanhf(c);
    cstate[i] = c;
    hstate[i] = hn;
    if (yout) yout[i] = hn;
}

// ---------------- output head: per-row (wave) Linear(128->64)+LN+ReLU+Linear(64->1)
__global__ __launch_bounds__(64) void out_head(const float* __restrict__ y,
                                               const float* __restrict__ w1,
                                               const float* __restrict__ b1,
                                               const float* __restrict__ g,
                                               const float* __restrict__ be,
                                               const float* __restrict__ w2,
                                               const float* __restrict__ b2,
                                               float* __restrict__ out) {
    int r = blockIdx.x;  // 0..8191
    int j = threadIdx.x; // 0..63
    const float* yr = y + (int64_t)r * 128;
    float acc = b1[j];
    for (int k = 0; k < 128; ++k) acc += yr[k] * w1[k * 64 + j];
    float s = acc;
    for (int off = 32; off; off >>= 1) s += __shfl_xor(s, off, 64);
    float mu = s * (1.f / 64.f);
    float d = acc - mu;
    float vs = d * d;
    for (int off = 32; off; off >>= 1) vs += __shfl_xor(vs, off, 64);
    float var = vs * (1.f / 64.f);
    float z = fmaxf(d * rsqrtf(var + EPS) * g[j] + be[j], 0.f);
    float p = z * w2[j];
    for (int off = 32; off; off >>= 1) p += __shfl_xor(p, off, 64);
    if (j == 0) out[r] = p + b2[0];
}

extern "C" void kernel_launch(void* const* d_in, const int* in_sizes, int n_in,
                              void* d_out, int out_size, void* d_ws, size_t ws_size,
                              hipStream_t stream) {
    const float* x    = (const float*)d_in[0];
    const int*   eidx = (const int*)d_in[1];
    const float* ewt  = (const float*)d_in[2];
    const float* efeat= (const float*)d_in[3];
    const float* w_in = (const float*)d_in[4];
    const float* b_in = (const float*)d_in[5];
    const float* lng  = (const float*)d_in[6];
    const float* lnb  = (const float*)d_in[7];
    const float* we1  = (const float*)d_in[8];
    const float* be1  = (const float*)d_in[9];
    const float* we2  = (const float*)d_in[10];
    const float* be2  = (const float*)d_in[11];
    const float* gcnw = (const float*)d_in[12];
    const float* gcnb = (const float*)d_in[13];
    const float* bng  = (const float*)d_in[14];
    const float* bnb  = (const float*)d_in[15];
    const float* wih  = (const float*)d_in[16];
    const float* whh  = (const float*)d_in[17];
    const float* bih  = (const float*)d_in[18];
    const float* bhh  = (const float*)d_in[19];
    const float* wo1  = (const float*)d_in[20];
    const float* bo1  = (const float*)d_in[21];
    const float* lnog = (const float*)d_in[22];
    const float* lnob = (const float*)d_in[23];
    const float* wo2  = (const float*)d_in[24];
    const float* bo2  = (const float*)d_in[25];
    float* out = (float*)d_out;

    // workspace layout (floats)
    float* p = (float*)d_ws;
    float* hcur   = p; p += 16777216;  // [16][8192][128]
    float* hw     = p; p += 16777216;  // [16][8192][128] (reused as LSTM layer-1 outputs)
    float* Apart  = p; p += 2097152;   // [16][1024][128]
    float* gates  = p; p += 4194304;   // [8192][512]
    float* hstate = p; p += 1048576;   // [8192][128]
    float* cstate = p; p += 1048576;
    float* ew     = p; p += 32768;
    float* dis    = p; p += 8192;
    float* Adense = p; p += 1048576;   // [1024][1024]
    float* wihT   = p; p += 131072;    // [2][128][512]
    float* whhT   = p; p += 131072;
    float* bsum   = p; p += 1024;      // [2][512]

    const int* srcI = eidx;
    const int* dstI = eidx + 32768;

    // graph preprocessing
    edge_att<<<128, 256, 0, stream>>>(efeat, we1, be1, we2, be2, ewt, ew);
    deg_init<<<32, 256, 0, stream>>>(dis);
    deg_acc<<<128, 256, 0, stream>>>(dstI, ew, dis);
    make_dis<<<32, 256, 0, stream>>>(dis);
    hipMemsetAsync(Adense, 0, 1048576 * sizeof(float), stream);
    scatterA<<<128, 256, 0, stream>>>(srcI, dstI, ew, dis, Adense);

    // input projection -> hcur (only rows k<23 of xf are used)
    in_proj_ln<<<23552, 128, 0, stream>>>(x, w_in, b_in, lng, lnb, hcur);

    // GCN layers (all 16 timesteps batched)
    for (int l = 0; l < 4; ++l) {
        dim3 g1(2048, 2, 1);
        gemm_f32<false, false><<<g1, 256, 0, stream>>>(
            hcur, nullptr, gcnw + l * 16384, nullptr, nullptr, hw,
            131072, 128, 128, 128, 128, 128, 0, 0, 0);
        dim3 g2(16, 2, 16);
        gemm_f32<false, false><<<g2, 256, 0, stream>>>(
            Adense, nullptr, hw, nullptr, nullptr, Apart,
            1024, 128, 1024, 1024, 128, 128, 0, (int64_t)8192 * 128, (int64_t)1024 * 128);
        gcn_combine<<<65536, 256, 0, stream>>>(hw, Apart, dis,
                                               gcnb + l * 128, bng + l * 128, bnb + l * 128, hcur);
    }

    // LSTM weight prep
    transpose_512x128<<<512, 256, 0, stream>>>(wih, wihT);
    transpose_512x128<<<512, 256, 0, stream>>>(whh, whhT);
    bias_sum<<<4, 256, 0, stream>>>(bih, bhh, bsum);

    // LSTM layer 1: input hcur[t], output -> hw[t]
    hipMemsetAsync(hstate, 0, 1048576 * sizeof(float), stream);
    hipMemsetAsync(cstate, 0, 1048576 * sizeof(float), stream);
    for (int t = 0; t < 16; ++t) {
        dim3 g3(128, 8, 1);
        gemm_f32<true, true><<<g3, 256, 0, stream>>>(
            hcur + (int64_t)t * 1048576, hstate, wihT, whhT, bsum, gates,
            8192, 512, 128, 128, 512, 512, 0, 0, 0);
        lstm_cell<<<4096, 256, 0, stream>>>(gates, hstate, cstate, hw + (int64_t)t * 1048576);
    }
    // LSTM layer 2: input hw[t], only final h needed
    hipMemsetAsync(hstate, 0, 1048576 * sizeof(float), stream);
    hipMemsetAsync(cstate, 0, 1048576 * sizeof(float), stream);
    for (int t = 0; t < 16; ++t) {
        dim3 g3(128, 8, 1);
        gemm_f32<true, true><<<g3, 256, 0, stream>>>(
            hw + (int64_t)t * 1048576, hstate, wihT + 65536, whhT + 65536, bsum + 512, gates,
            8192, 512, 128, 128, 512, 512, 0, 0, 0);
        lstm_cell<<<4096, 256, 0, stream>>>(gates, hstate, cstate, nullptr);
    }

    // output head
    out_head<<<8192, 64, 0, stream>>>(hstate, wo1, bo1, lnog, lnob, wo2, bo2, out);
}

// Round 2
// 1023.389 us; speedup vs baseline: 2.0930x; 2.0930x over previous
//
#include <hip/hip_runtime.h>
#include <cstdint>

// B=8, S=16, N=1024, F=16, H=128, E=32768, L=4, BN=8192
#define EPS 1e-5f

typedef unsigned short ushort_t;
typedef __bf16 bf16x8 __attribute__((ext_vector_type(8)));
typedef float f32x4 __attribute__((ext_vector_type(4)));

__device__ __forceinline__ float sigm(float x) { return 1.f / (1.f + expf(-x)); }
__device__ __forceinline__ unsigned short f2bf(float f) {
    unsigned int u = __builtin_bit_cast(unsigned int, f);
    return (unsigned short)((u + 0x7fffu + ((u >> 16) & 1u)) >> 16);
}
__device__ __forceinline__ float bf2f(unsigned short s) {
    unsigned int u = ((unsigned int)s) << 16;
    return __builtin_bit_cast(float, u);
}

// ---------------- edge attention
__global__ __launch_bounds__(256) void edge_att(const float* __restrict__ ef,
                                                const float* __restrict__ we1,
                                                const float* __restrict__ be1,
                                                const float* __restrict__ we2,
                                                const float* __restrict__ be2,
                                                const float* __restrict__ ewin,
                                                float* __restrict__ ew) {
    int e = blockIdx.x * blockDim.x + threadIdx.x;
    if (e >= 32768) return;
    float x = ef[e];
    float acc = 0.f;
    for (int h = 0; h < 128; ++h) {
        float v = fmaxf(x * we1[h] + be1[h], 0.f);
        acc += v * we2[h];
    }
    ew[e] = ewin[e] * sigm(acc + be2[0]);
}

__global__ __launch_bounds__(256) void deg_init(float* __restrict__ deg) {
    int i = blockIdx.x * blockDim.x + threadIdx.x;
    if (i < 8192) deg[i] = 1.0f;
}
__global__ __launch_bounds__(256) void deg_acc(const int* __restrict__ dst,
                                               const float* __restrict__ ew,
                                               float* __restrict__ deg) {
    int e = blockIdx.x * blockDim.x + threadIdx.x;
    if (e < 32768) atomicAdd(&deg[dst[e]], ew[e]);
}
__global__ __launch_bounds__(256) void make_dis(float* __restrict__ deg) {
    int i = blockIdx.x * blockDim.x + threadIdx.x;
    if (i < 8192) { float d = deg[i]; deg[i] = (d > 0.f) ? rsqrtf(d) : 0.f; }
}
__global__ __launch_bounds__(256) void scatterA(const int* __restrict__ src,
                                                const int* __restrict__ dst,
                                                const float* __restrict__ ew,
                                                const float* __restrict__ dis,
                                                float* __restrict__ A) {
    int e = blockIdx.x * blockDim.x + threadIdx.x;
    if (e >= 32768) return;
    int s = src[e], d = dst[e];
    atomicAdd(&A[d * 1024 + s], dis[s] * ew[e] * dis[d]);
}

// ---------------- fp32 -> bf16 converters
__global__ __launch_bounds__(256) void convF2B(const float* __restrict__ s,
                                               ushort_t* __restrict__ d, int n) {
    int i = blockIdx.x * blockDim.x + threadIdx.x;
    if (i < n) d[i] = f2bf(s[i]);
}
// gcnw [l][in][out] -> gcnwT [l][out][in] bf16
__global__ __launch_bounds__(256) void convW(const float* __restrict__ w,
                                             ushort_t* __restrict__ wt) {
    int i = blockIdx.x * blockDim.x + threadIdx.x;  // 4*128*128
    if (i >= 65536) return;
    int l = i >> 14, rem = i & 16383, in = rem >> 7, out = rem & 127;
    wt[l * 16384 + out * 128 + in] = f2bf(w[i]);
}
__global__ __launch_bounds__(256) void bias_sum(const float* __restrict__ bih,
                                                const float* __restrict__ bhh,
                                                float* __restrict__ bs) {
    int i = blockIdx.x * blockDim.x + threadIdx.x;
    if (i < 1024) bs[i] = bih[i] + bhh[i];
}

// ---------------- input projection + LN + ReLU -> hcur (fp32) + hcur_bf
__global__ __launch_bounds__(128) void in_proj_ln(const float* __restrict__ x,
                                                  const float* __restrict__ w,
                                                  const float* __restrict__ bias,
                                                  const float* __restrict__ g,
                                                  const float* __restrict__ be,
                                                  float* __restrict__ hcur,
                                                  ushort_t* __restrict__ hb) {
    int r = blockIdx.x;            // k*1024 + n, k in [0,23)
    int h = threadIdx.x;
    int k = r >> 10, n = r & 1023;
    __shared__ float xs[16];
    __shared__ float red[128];
    if (h < 16) xs[h] = x[(int64_t)r * 16 + h];
    __syncthreads();
    float acc = bias[h];
#pragma unroll
    for (int f = 0; f < 16; ++f) acc += xs[f] * w[f * 128 + h];
    red[h] = acc; __syncthreads();
    for (int off = 64; off; off >>= 1) { if (h < off) red[h] += red[h + off]; __syncthreads(); }
    float mu = red[0] * (1.f / 128.f); __syncthreads();
    float d = acc - mu; red[h] = d * d; __syncthreads();
    for (int off = 64; off; off >>= 1) { if (h < off) red[h] += red[h + off]; __syncthreads(); }
    float var = red[0] * (1.f / 128.f);
    float v = fmaxf(d * rsqrtf(var + EPS) * g[h] + be[h], 0.f);
    ushort_t vb = f2bf(v);
#pragma unroll
    for (int b = 0; b < 8; ++b) {
        int t = k - b;
        if (t >= 0 && t < 16) {
            int64_t idx = ((int64_t)t * 8192 + b * 1024 + n) * 128 + h;
            hcur[idx] = v;
            hb[idx] = vb;
        }
    }
}

// ---------------- bf16 MFMA GEMM: C = A0@BT0^T (+ A1@BT1^T)
// A [M][K] bf16 row-major, BT [N][K] bf16 row-major. Tiles: TM x 128, BK=64, 4 waves.
// MODE 0: C fp32 [M][ldc] (+ bz*bsC)
// MODE 1: C bf16 [M][128] AND transposed bf16 CT[t][col][bn] for bn<1024 (t=row>>13, bn=row&8191)
template <int TM, int MODE>
__global__ __launch_bounds__(256) void gemm_bf16(
    const ushort_t* __restrict__ A0, const ushort_t* __restrict__ A1,
    const ushort_t* __restrict__ BT0, const ushort_t* __restrict__ BT1,
    float* __restrict__ Cf, ushort_t* __restrict__ Cb, ushort_t* __restrict__ CT,
    int K, int ldc, int64_t bsA, int64_t bsBT, int64_t bsC) {
    constexpr int MR = TM / 32;                 // A frags per wave
    __shared__ __align__(16) char AsB[TM * 128];   // TM rows x 64 bf16 (swizzled)
    __shared__ __align__(16) char BsB[128 * 128];  // 128 cols x 64 bf16 (swizzled)
    const int tid = threadIdx.x;
    const int lane = tid & 63;
    const int wid = tid >> 6;
    const int wr = wid >> 1, wc = wid & 1;
    const int64_t row0 = (int64_t)blockIdx.x * TM;
    const int col0 = blockIdx.y * 128;
    const int bz = blockIdx.z;

    f32x4 acc[MR][4];
#pragma unroll
    for (int m = 0; m < MR; ++m)
#pragma unroll
        for (int n = 0; n < 4; ++n) acc[m][n] = {0.f, 0.f, 0.f, 0.f};

    const int nsrc = (A1 != nullptr) ? 2 : 1;
    for (int s = 0; s < nsrc; ++s) {
        const ushort_t* Ap = (s == 0 ? A0 : A1) + bz * bsA;
        const ushort_t* Bp = (s == 0 ? BT0 : BT1) + bz * bsBT;
        for (int k0 = 0; k0 < K; k0 += 64) {
            __syncthreads();
#pragma unroll
            for (int i = 0; i < TM / 32; ++i) {      // TM*8 segments of 16B
                int id = i * 256 + tid;
                int r = id >> 3, sg = id & 7;
                uint4 v = *(const uint4*)(Ap + (row0 + r) * (int64_t)K + k0 + sg * 8);
                *(uint4*)(AsB + r * 128 + ((sg * 16) ^ ((r & 7) << 4))) = v;
            }
#pragma unroll
            for (int i = 0; i < 4; ++i) {            // 1024 segments
                int id = i * 256 + tid;
                int r = id >> 3, sg = id & 7;
                uint4 v = *(const uint4*)(Bp + (int64_t)(col0 + r) * K + k0 + sg * 8);
                *(uint4*)(BsB + r * 128 + ((sg * 16) ^ ((r & 7) << 4))) = v;
            }
            __syncthreads();
#pragma unroll
            for (int kk = 0; kk < 2; ++kk) {
                bf16x8 af[MR], bfr[4];
#pragma unroll
                for (int m = 0; m < MR; ++m) {
                    int row = wr * (TM / 2) + m * 16 + (lane & 15);
                    af[m] = __builtin_bit_cast(
                        bf16x8, *(const uint4*)(AsB + row * 128 +
                                 ((kk * 64 + (lane >> 4) * 16) ^ ((row & 7) << 4))));
                }
#pragma unroll
                for (int n = 0; n < 4; ++n) {
                    int col = wc * 64 + n * 16 + (lane & 15);
                    bfr[n] = __builtin_bit_cast(
                        bf16x8, *(const uint4*)(BsB + col * 128 +
                                 ((kk * 64 + (lane >> 4) * 16) ^ ((col & 7) << 4))));
                }
#pragma unroll
                for (int m = 0; m < MR; ++m)
#pragma unroll
                    for (int n = 0; n < 4; ++n)
                        acc[m][n] = __builtin_amdgcn_mfma_f32_16x16x32_bf16(
                            af[m], bfr[n], acc[m][n], 0, 0, 0);
            }
        }
    }

    if (MODE == 0) {
        float* C = Cf + bz * bsC;
#pragma unroll
        for (int m = 0; m < MR; ++m) {
            int64_t rb = row0 + wr * (TM / 2) + m * 16 + ((lane >> 4) * 4);
#pragma unroll
            for (int n = 0; n < 4; ++n) {
                int c = col0 + wc * 64 + n * 16 + (lane & 15);
#pragma unroll
                for (int e = 0; e < 4; ++e) C[(rb + e) * ldc + c] = acc[m][n][e];
            }
        }
    } else {
#pragma unroll
        for (int m = 0; m < MR; ++m) {
            int64_t rb = row0 + wr * (TM / 2) + m * 16 + ((lane >> 4) * 4);
#pragma unroll
            for (int n = 0; n < 4; ++n) {
                int c = col0 + wc * 64 + n * 16 + (lane & 15);
#pragma unroll
                for (int e = 0; e < 4; ++e) Cb[(rb + e) * 128 + c] = f2bf(acc[m][n][e]);
            }
        }
        if ((row0 & 8191) < 1024) {
            int t = (int)(row0 >> 13);
#pragma unroll
            for (int m = 0; m < MR; ++m) {
                int bnb = (int)(row0 & 8191) + wr * (TM / 2) + m * 16 + (lane >> 4) * 4;
#pragma unroll
                for (int n = 0; n < 4; ++n) {
                    int c = col0 + wc * 64 + n * 16 + (lane & 15);
                    ushort4 u;
                    u.x = f2bf(acc[m][n][0]); u.y = f2bf(acc[m][n][1]);
                    u.z = f2bf(acc[m][n][2]); u.w = f2bf(acc[m][n][3]);
                    *(ushort4*)(CT + ((int64_t)t * 128 + c) * 1024 + bnb) = u;
                }
            }
        }
    }
}

// ---------------- GCN combine: h = relu((sl*hw + Apart + b)*bn_scale + bn_b) + h
__global__ __launch_bounds__(256) void gcn_combine(const ushort_t* __restrict__ hwb,
                                                   const float* __restrict__ Apart,
                                                   const float* __restrict__ dis,
                                                   const float* __restrict__ gcnb,
                                                   const float* __restrict__ bng,
                                                   const float* __restrict__ bnb,
                                                   float* __restrict__ hcur,
                                                   ushort_t* __restrict__ hb) {
    int64_t i = (int64_t)blockIdx.x * blockDim.x + threadIdx.x;  // 16*8192*128
    int h = (int)(i & 127);
    int64_t rt = i >> 7;
    int bn = (int)(rt & 8191);
    int t = (int)(rt >> 13);
    float sl = dis[bn] * dis[bn];
    float m = sl * bf2f(hwb[i]) + gcnb[h];
    if (bn < 1024) m += Apart[((int64_t)t * 1024 + bn) * 128 + h];
    float scale = bng[h] * rsqrtf(1.f + EPS);
    float v = fmaxf(m * scale + bnb[h], 0.f) + hcur[i];
    hcur[i] = v;
    hb[i] = f2bf(v);
}

// ---------------- LSTM cell (bias folded in), writes bf16 h (+ optional bf16 y)
__global__ __launch_bounds__(256) void lstm_cell(const float* __restrict__ gates,
                                                 const float* __restrict__ bs,
                                                 float* __restrict__ cstate,
                                                 ushort_t* __restrict__ hb,
                                                 ushort_t* __restrict__ yb) {
    int i = blockIdx.x * blockDim.x + threadIdx.x;  // 8192*128
    int h = i & 127;
    int r = i >> 7;
    const float* g = gates + (int64_t)r * 512;
    float ig = sigm(g[h] + bs[h]);
    float fg = sigm(g[128 + h] + bs[128 + h]);
    float gg = tanhf(g[256 + h] + bs[256 + h]);
    float og = sigm(g[384 + h] + bs[384 + h]);
    float c = fg * cstate[i] + ig * gg;
    float hn = og * tanhf(c);
    cstate[i] = c;
    ushort_t hv = f2bf(hn);
    hb[i] = hv;
    if (yb) yb[i] = hv;
}

// ---------------- output head
__global__ __launch_bounds__(64) void out_head(const ushort_t* __restrict__ y,
                                               const float* __restrict__ w1,
                                               const float* __restrict__ b1,
                                               const float* __restrict__ g,
                                               const float* __restrict__ be,
                                               const float* __restrict__ w2,
                                               const float* __restrict__ b2,
                                               float* __restrict__ out) {
    int r = blockIdx.x;  // 0..8191
    int j = threadIdx.x; // 0..63
    const ushort_t* yr = y + (int64_t)r * 128;
    float acc = b1[j];
    for (int k = 0; k < 128; ++k) acc += bf2f(yr[k]) * w1[k * 64 + j];
    float s = acc;
    for (int off = 32; off; off >>= 1) s += __shfl_xor(s, off, 64);
    float mu = s * (1.f / 64.f);
    float d = acc - mu;
    float vs = d * d;
    for (int off = 32; off; off >>= 1) vs += __shfl_xor(vs, off, 64);
    float var = vs * (1.f / 64.f);
    float z = fmaxf(d * rsqrtf(var + EPS) * g[j] + be[j], 0.f);
    float p = z * w2[j];
    for (int off = 32; off; off >>= 1) p += __shfl_xor(p, off, 64);
    if (j == 0) out[r] = p + b2[0];
}

extern "C" void kernel_launch(void* const* d_in, const int* in_sizes, int n_in,
                              void* d_out, int out_size, void* d_ws, size_t ws_size,
                              hipStream_t stream) {
    const float* x    = (const float*)d_in[0];
    const int*   eidx = (const int*)d_in[1];
    const float* ewt  = (const float*)d_in[2];
    const float* efeat= (const float*)d_in[3];
    const float* w_in = (const float*)d_in[4];
    const float* b_in = (const float*)d_in[5];
    const float* lng  = (const float*)d_in[6];
    const float* lnb  = (const float*)d_in[7];
    const float* we1  = (const float*)d_in[8];
    const float* be1  = (const float*)d_in[9];
    const float* we2  = (const float*)d_in[10];
    const float* be2  = (const float*)d_in[11];
    const float* gcnw = (const float*)d_in[12];
    const float* gcnb = (const float*)d_in[13];
    const float* bng  = (const float*)d_in[14];
    const float* bnb  = (const float*)d_in[15];
    const float* wih  = (const float*)d_in[16];
    const float* whh  = (const float*)d_in[17];
    const float* bih  = (const float*)d_in[18];
    const float* bhh  = (const float*)d_in[19];
    const float* wo1  = (const float*)d_in[20];
    const float* bo1  = (const float*)d_in[21];
    const float* lnog = (const float*)d_in[22];
    const float* lnob = (const float*)d_in[23];
    const float* wo2  = (const float*)d_in[24];
    const float* bo2  = (const float*)d_in[25];
    float* out = (float*)d_out;

    // ---- workspace layout (byte offsets in MB), total 154MB
    char* W = (char*)d_ws;
    float*    hcur      = (float*)(W);                         // 64MB [16][8192][128]
    float*    Apart     = (float*)(W + (64ll << 20));          // 8MB  [16][1024][128]
    float*    Adense    = (float*)(W + (72ll << 20));          // 4MB  [1024][1024]
    ushort_t* Adense_bf = (ushort_t*)(W + (76ll << 20));       // 2MB
    ushort_t* hwT       = (ushort_t*)(W + (78ll << 20));       // 4MB  [16][128][1024]
    float*    gates     = (float*)(W + (64ll << 20));          // 16MB, aliases GCN-dead bufs
    float*    cstate    = (float*)(W + (82ll << 20));          // 4MB
    float*    ew        = (float*)(W + (86ll << 20));          // 128KB
    float*    dis       = (float*)(W + (86ll << 20) + 131072); // 32KB
    float*    bsum      = (float*)(W + (86ll << 20) + 196608); // 4KB [2][512]
    ushort_t* gcnwT     = (ushort_t*)(W + (86ll << 20) + 262144);  // 128KB [4][128][128]
    ushort_t* wih_bf    = (ushort_t*)(W + (86ll << 20) + 524288);  // 256KB [2][512][128]
    ushort_t* whh_bf    = (ushort_t*)(W + (86ll << 20) + 786432);  // 256KB
    ushort_t* hcur_bf   = (ushort_t*)(W + (88ll << 20));       // 32MB [16][8192][128]
    ushort_t* hw_bf     = (ushort_t*)(W + (120ll << 20));      // 32MB (also LSTM-1 y storage)
    ushort_t* h_bf      = (ushort_t*)(W + (152ll << 20));      // 2MB  [8192][128]

    const int* srcI = eidx;
    const int* dstI = eidx + 32768;

    // graph preprocessing
    edge_att<<<128, 256, 0, stream>>>(efeat, we1, be1, we2, be2, ewt, ew);
    deg_init<<<32, 256, 0, stream>>>(dis);
    deg_acc<<<128, 256, 0, stream>>>(dstI, ew, dis);
    make_dis<<<32, 256, 0, stream>>>(dis);
    hipMemsetAsync(Adense, 0, 1048576 * sizeof(float), stream);
    scatterA<<<128, 256, 0, stream>>>(srcI, dstI, ew, dis, Adense);
    convF2B<<<4096, 256, 0, stream>>>(Adense, Adense_bf, 1048576);

    // weight conversions
    convW<<<256, 256, 0, stream>>>(gcnw, gcnwT);
    convF2B<<<512, 256, 0, stream>>>(wih, wih_bf, 131072);
    convF2B<<<512, 256, 0, stream>>>(whh, whh_bf, 131072);
    bias_sum<<<4, 256, 0, stream>>>(bih, bhh, bsum);

    // input projection
    in_proj_ln<<<23552, 128, 0, stream>>>(x, w_in, b_in, lng, lnb, hcur, hcur_bf);

    // GCN layers
    for (int l = 0; l < 4; ++l) {
        gemm_bf16<128, 1><<<dim3(1024, 1, 1), 256, 0, stream>>>(
            hcur_bf, nullptr, gcnwT + l * 16384, nullptr,
            nullptr, hw_bf, hwT, 128, 128, 0, 0, 0);
        gemm_bf16<64, 0><<<dim3(16, 1, 16), 256, 0, stream>>>(
            Adense_bf, nullptr, hwT, nullptr,
            Apart, nullptr, nullptr, 1024, 128, 0, 131072, 131072);
        gcn_combine<<<65536, 256, 0, stream>>>(hw_bf, Apart, dis,
                                               gcnb + l * 128, bng + l * 128, bnb + l * 128,
                                               hcur, hcur_bf);
    }

    // LSTM layer 1: x = hcur_bf[t], y -> hw_bf[t]
    hipMemsetAsync(cstate, 0, 1048576 * sizeof(float), stream);
    hipMemsetAsync(h_bf, 0, 1048576 * sizeof(ushort_t), stream);
    for (int t = 0; t < 16; ++t) {
        gemm_bf16<128, 0><<<dim3(64, 4, 1), 256, 0, stream>>>(
            hcur_bf + (int64_t)t * 1048576, h_bf, wih_bf, whh_bf,
            gates, nullptr, nullptr, 128, 512, 0, 0, 0);
        lstm_cell<<<4096, 256, 0, stream>>>(gates, bsum, cstate, h_bf,
                                            hw_bf + (int64_t)t * 1048576);
    }
    // LSTM layer 2: x = hw_bf[t] (y of layer 1), only final h needed
    hipMemsetAsync(cstate, 0, 1048576 * sizeof(float), stream);
    hipMemsetAsync(h_bf, 0, 1048576 * sizeof(ushort_t), stream);
    for (int t = 0; t < 16; ++t) {
        gemm_bf16<128, 0><<<dim3(64, 4, 1), 256, 0, stream>>>(
            hw_bf + (int64_t)t * 1048576, h_bf, wih_bf + 65536, whh_bf + 65536,
            gates, nullptr, nullptr, 128, 512, 0, 0, 0);
        lstm_cell<<<4096, 256, 0, stream>>>(gates, bsum + 512, cstate, h_bf, nullptr);
    }

    // output head
    out_head<<<8192, 64, 0, stream>>>(h_bf, wo1, bo1, lnog, lnob, wo2, bo2, out);
}

// Round 3
// 761.615 us; speedup vs baseline: 2.8124x; 1.3437x over previous
//
#include <hip/hip_runtime.h>
#include <cstdint>

// B=8, S=16, N=1024, F=16, H=128, E=32768, L=4, BN=8192
#define EPS 1e-5f

typedef unsigned short ushort_t;
typedef __bf16 bf16x8 __attribute__((ext_vector_type(8)));
typedef float f32x4 __attribute__((ext_vector_type(4)));

__device__ __forceinline__ float sigm(float x) { return 1.f / (1.f + expf(-x)); }
__device__ __forceinline__ unsigned short f2bf(float f) {
    unsigned int u = __builtin_bit_cast(unsigned int, f);
    return (unsigned short)((u + 0x7fffu + ((u >> 16) & 1u)) >> 16);
}
__device__ __forceinline__ float bf2f(unsigned short s) {
    unsigned int u = ((unsigned int)s) << 16;
    return __builtin_bit_cast(float, u);
}

// ---------------- edge attention
__global__ __launch_bounds__(256) void edge_att(const float* __restrict__ ef,
                                                const float* __restrict__ we1,
                                                const float* __restrict__ be1,
                                                const float* __restrict__ we2,
                                                const float* __restrict__ be2,
                                                const float* __restrict__ ewin,
                                                float* __restrict__ ew) {
    int e = blockIdx.x * blockDim.x + threadIdx.x;
    if (e >= 32768) return;
    float x = ef[e];
    float acc = 0.f;
    for (int h = 0; h < 128; ++h) {
        float v = fmaxf(x * we1[h] + be1[h], 0.f);
        acc += v * we2[h];
    }
    ew[e] = ewin[e] * sigm(acc + be2[0]);
}

__global__ __launch_bounds__(256) void deg_init(float* __restrict__ deg) {
    int i = blockIdx.x * blockDim.x + threadIdx.x;
    if (i < 8192) deg[i] = 1.0f;
}
__global__ __launch_bounds__(256) void deg_acc(const int* __restrict__ dst,
                                               const float* __restrict__ ew,
                                               float* __restrict__ deg) {
    int e = blockIdx.x * blockDim.x + threadIdx.x;
    if (e < 32768) atomicAdd(&deg[dst[e]], ew[e]);
}
__global__ __launch_bounds__(256) void make_dis(float* __restrict__ deg) {
    int i = blockIdx.x * blockDim.x + threadIdx.x;
    if (i < 8192) { float d = deg[i]; deg[i] = (d > 0.f) ? rsqrtf(d) : 0.f; }
}
__global__ __launch_bounds__(256) void scatterA(const int* __restrict__ src,
                                                const int* __restrict__ dst,
                                                const float* __restrict__ ew,
                                                const float* __restrict__ dis,
                                                float* __restrict__ A) {
    int e = blockIdx.x * blockDim.x + threadIdx.x;
    if (e >= 32768) return;
    int s = src[e], d = dst[e];
    atomicAdd(&A[d * 1024 + s], dis[s] * ew[e] * dis[d]);
}

// ---------------- converters
__global__ __launch_bounds__(256) void convF2B(const float* __restrict__ s,
                                               ushort_t* __restrict__ d, int n) {
    int i = blockIdx.x * blockDim.x + threadIdx.x;
    if (i < n) d[i] = f2bf(s[i]);
}
// gcnw [l][in][out] -> gcnwT [l][out][in] bf16
__global__ __launch_bounds__(256) void convW(const float* __restrict__ w,
                                             ushort_t* __restrict__ wt) {
    int i = blockIdx.x * blockDim.x + threadIdx.x;  // 4*128*128
    if (i >= 65536) return;
    int l = i >> 14, rem = i & 16383, in = rem >> 7, out = rem & 127;
    wt[l * 16384 + out * 128 + in] = f2bf(w[i]);
}
__global__ __launch_bounds__(256) void bias_sum(const float* __restrict__ bih,
                                                const float* __restrict__ bhh,
                                                float* __restrict__ bs) {
    int i = blockIdx.x * blockDim.x + threadIdx.x;
    if (i < 1024) bs[i] = bih[i] + bhh[i];
}

// ---------------- input projection + LN + ReLU -> hcur_bf only
__global__ __launch_bounds__(128) void in_proj_ln(const float* __restrict__ x,
                                                  const float* __restrict__ w,
                                                  const float* __restrict__ bias,
                                                  const float* __restrict__ g,
                                                  const float* __restrict__ be,
                                                  ushort_t* __restrict__ hb) {
    int r = blockIdx.x;            // k*1024 + n, k in [0,23)
    int h = threadIdx.x;
    int k = r >> 10, n = r & 1023;
    __shared__ float xs[16];
    __shared__ float red[128];
    if (h < 16) xs[h] = x[(int64_t)r * 16 + h];
    __syncthreads();
    float acc = bias[h];
#pragma unroll
    for (int f = 0; f < 16; ++f) acc += xs[f] * w[f * 128 + h];
    red[h] = acc; __syncthreads();
    for (int off = 64; off; off >>= 1) { if (h < off) red[h] += red[h + off]; __syncthreads(); }
    float mu = red[0] * (1.f / 128.f); __syncthreads();
    float d = acc - mu; red[h] = d * d; __syncthreads();
    for (int off = 64; off; off >>= 1) { if (h < off) red[h] += red[h + off]; __syncthreads(); }
    float var = red[0] * (1.f / 128.f);
    float v = fmaxf(d * rsqrtf(var + EPS) * g[h] + be[h], 0.f);
    ushort_t vb = f2bf(v);
#pragma unroll
    for (int b = 0; b < 8; ++b) {
        int t = k - b;
        if (t >= 0 && t < 16)
            hb[((int64_t)t * 8192 + b * 1024 + n) * 128 + h] = vb;
    }
}

// ---------------- feature GEMM for rows<1024 per t, transposed output hwT[t][col][bn]
__global__ __launch_bounds__(256) void gemm_feat_t(const ushort_t* __restrict__ Hin,
                                                   const ushort_t* __restrict__ Wt,
                                                   ushort_t* __restrict__ hwT) {
    __shared__ __align__(16) char AsB[32768];
    __shared__ __align__(16) char BsB[32768];
    const int tid = threadIdx.x, lane = tid & 63, wid = tid >> 6;
    const int wr = wid >> 1, wc = wid & 1, q = lane >> 4, l15 = lane & 15;
    const int t = blockIdx.y;
    const int row0 = blockIdx.x * 128;
    const ushort_t* Ap = Hin + (int64_t)t * 1048576 + (int64_t)row0 * 128;
    f32x4 acc[4][4];
#pragma unroll
    for (int m = 0; m < 4; ++m)
#pragma unroll
        for (int n = 0; n < 4; ++n) acc[m][n] = f32x4{0.f, 0.f, 0.f, 0.f};
#pragma unroll
    for (int i = 0; i < 8; ++i) {
        int id = i * 256 + tid; int r = id >> 4, sg = id & 15;
        uint4 va = *(const uint4*)(Ap + r * 128 + sg * 8);
        *(uint4*)(AsB + r * 256 + ((sg * 16) ^ ((r & 7) << 4))) = va;
        uint4 vb = *(const uint4*)(Wt + r * 128 + sg * 8);
        *(uint4*)(BsB + r * 256 + ((sg * 16) ^ ((r & 7) << 4))) = vb;
    }
    __syncthreads();
#pragma unroll
    for (int kk = 0; kk < 4; ++kk) {
        bf16x8 af[4], bfr[4];
#pragma unroll
        for (int m = 0; m < 4; ++m) {
            int row = wr * 64 + m * 16 + l15;
            af[m] = __builtin_bit_cast(bf16x8,
                *(const uint4*)(AsB + row * 256 + ((kk * 64 + q * 16) ^ ((row & 7) << 4))));
        }
#pragma unroll
        for (int n = 0; n < 4; ++n) {
            int col = wc * 64 + n * 16 + l15;
            bfr[n] = __builtin_bit_cast(bf16x8,
                *(const uint4*)(BsB + col * 256 + ((kk * 64 + q * 16) ^ ((col & 7) << 4))));
        }
#pragma unroll
        for (int m = 0; m < 4; ++m)
#pragma unroll
            for (int n = 0; n < 4; ++n)
                acc[m][n] = __builtin_amdgcn_mfma_f32_16x16x32_bf16(af[m], bfr[n], acc[m][n], 0, 0, 0);
    }
#pragma unroll
    for (int m = 0; m < 4; ++m) {
        int bn = row0 + wr * 64 + m * 16 + q * 4;
#pragma unroll
        for (int n = 0; n < 4; ++n) {
            int col = wc * 64 + n * 16 + l15;
            ushort4 u;
            u.x = f2bf(acc[m][n][0]); u.y = f2bf(acc[m][n][1]);
            u.z = f2bf(acc[m][n][2]); u.w = f2bf(acc[m][n][3]);
            *(ushort4*)(hwT + ((int64_t)t * 128 + col) * 1024 + bn) = u;
        }
    }
}

// ---------------- adjacency GEMM: Apart[t] = Adense_bf @ hw[t]  (B as hwT [col][bn])
__global__ __launch_bounds__(256) void gemm_adj(const ushort_t* __restrict__ Abf,
                                                const ushort_t* __restrict__ hwT,
                                                float* __restrict__ Apart) {
    __shared__ __align__(16) char AsB[8192];    // 64 rows x 64k
    __shared__ __align__(16) char BsB[16384];   // 128 cols x 64k
    const int tid = threadIdx.x, lane = tid & 63, wid = tid >> 6;
    const int wr = wid >> 1, wc = wid & 1, q = lane >> 4, l15 = lane & 15;
    const int row0 = blockIdx.x * 64;
    const int t = blockIdx.z;
    const ushort_t* Bp = hwT + (int64_t)t * 131072;
    f32x4 acc[2][4];
#pragma unroll
    for (int m = 0; m < 2; ++m)
#pragma unroll
        for (int n = 0; n < 4; ++n) acc[m][n] = f32x4{0.f, 0.f, 0.f, 0.f};
    for (int k0 = 0; k0 < 1024; k0 += 64) {
        __syncthreads();
#pragma unroll
        for (int i = 0; i < 2; ++i) {
            int id = i * 256 + tid; int r = id >> 3, sg = id & 7;
            uint4 v = *(const uint4*)(Abf + (int64_t)(row0 + r) * 1024 + k0 + sg * 8);
            *(uint4*)(AsB + r * 128 + ((sg * 16) ^ ((r & 7) << 4))) = v;
        }
#pragma unroll
        for (int i = 0; i < 4; ++i) {
            int id = i * 256 + tid; int r = id >> 3, sg = id & 7;
            uint4 v = *(const uint4*)(Bp + (int64_t)r * 1024 + k0 + sg * 8);
            *(uint4*)(BsB + r * 128 + ((sg * 16) ^ ((r & 7) << 4))) = v;
        }
        __syncthreads();
#pragma unroll
        for (int kk = 0; kk < 2; ++kk) {
            bf16x8 af[2], bfr[4];
#pragma unroll
            for (int m = 0; m < 2; ++m) {
                int row = wr * 32 + m * 16 + l15;
                af[m] = __builtin_bit_cast(bf16x8,
                    *(const uint4*)(AsB + row * 128 + ((kk * 64 + q * 16) ^ ((row & 7) << 4))));
            }
#pragma unroll
            for (int n = 0; n < 4; ++n) {
                int col = wc * 64 + n * 16 + l15;
                bfr[n] = __builtin_bit_cast(bf16x8,
                    *(const uint4*)(BsB + col * 128 + ((kk * 64 + q * 16) ^ ((col & 7) << 4))));
            }
#pragma unroll
            for (int m = 0; m < 2; ++m)
#pragma unroll
                for (int n = 0; n < 4; ++n)
                    acc[m][n] = __builtin_amdgcn_mfma_f32_16x16x32_bf16(af[m], bfr[n], acc[m][n], 0, 0, 0);
        }
    }
#pragma unroll
    for (int m = 0; m < 2; ++m) {
        int rb = row0 + wr * 32 + m * 16 + q * 4;
#pragma unroll
        for (int n = 0; n < 4; ++n) {
            int c = wc * 64 + n * 16 + l15;
#pragma unroll
            for (int e = 0; e < 4; ++e)
                Apart[((int64_t)t * 1024 + rb + e) * 128 + c] = acc[m][n][e];
        }
    }
}

// ---------------- fused GCN layer: hw = Hin@W; h = relu((sl*hw + Apart + b)*scale + bnb) + Hin
// In-place on hcur_bf (block reads its rows fully into LDS before writing them).
__global__ __launch_bounds__(256) void gcn_fused(const ushort_t* __restrict__ Hin,
                                                 const ushort_t* __restrict__ Wt,
                                                 const float* __restrict__ Apart,
                                                 const float* __restrict__ dis,
                                                 const float* __restrict__ gcnb,
                                                 const float* __restrict__ bng,
                                                 const float* __restrict__ bnb,
                                                 ushort_t* __restrict__ Hout) {
    __shared__ __align__(16) char AsB[32768];
    __shared__ __align__(16) char BsB[32768];
    const int tid = threadIdx.x, lane = tid & 63, wid = tid >> 6;
    const int wr = wid >> 1, wc = wid & 1, q = lane >> 4, l15 = lane & 15;
    const int64_t row0 = (int64_t)blockIdx.x * 128;
    const ushort_t* Ap = Hin + row0 * 128;
    f32x4 acc[4][4];
#pragma unroll
    for (int m = 0; m < 4; ++m)
#pragma unroll
        for (int n = 0; n < 4; ++n) acc[m][n] = f32x4{0.f, 0.f, 0.f, 0.f};
#pragma unroll
    for (int i = 0; i < 8; ++i) {
        int id = i * 256 + tid; int r = id >> 4, sg = id & 15;
        uint4 va = *(const uint4*)(Ap + r * 128 + sg * 8);
        *(uint4*)(AsB + r * 256 + ((sg * 16) ^ ((r & 7) << 4))) = va;
        uint4 vb = *(const uint4*)(Wt + r * 128 + sg * 8);
        *(uint4*)(BsB + r * 256 + ((sg * 16) ^ ((r & 7) << 4))) = vb;
    }
    __syncthreads();
#pragma unroll
    for (int kk = 0; kk < 4; ++kk) {
        bf16x8 af[4], bfr[4];
#pragma unroll
        for (int m = 0; m < 4; ++m) {
            int row = wr * 64 + m * 16 + l15;
            af[m] = __builtin_bit_cast(bf16x8,
                *(const uint4*)(AsB + row * 256 + ((kk * 64 + q * 16) ^ ((row & 7) << 4))));
        }
#pragma unroll
        for (int n = 0; n < 4; ++n) {
            int col = wc * 64 + n * 16 + l15;
            bfr[n] = __builtin_bit_cast(bf16x8,
                *(const uint4*)(BsB + col * 256 + ((kk * 64 + q * 16) ^ ((col & 7) << 4))));
        }
#pragma unroll
        for (int m = 0; m < 4; ++m)
#pragma unroll
            for (int n = 0; n < 4; ++n)
                acc[m][n] = __builtin_amdgcn_mfma_f32_16x16x32_bf16(af[m], bfr[n], acc[m][n], 0, 0, 0);
    }
    const int bn0 = (int)(row0 & 8191);
    const int t = (int)(row0 >> 13);
    const bool hasA = bn0 < 1024;
    const float rs = rsqrtf(1.f + EPS);
#pragma unroll
    for (int n = 0; n < 4; ++n) {
        int col = wc * 64 + n * 16 + l15;
        float gb = gcnb[col], sc = bng[col] * rs, bb = bnb[col];
        int seg16 = (col >> 3) * 16, wb = (col & 7) * 2;
#pragma unroll
        for (int m = 0; m < 4; ++m) {
            int rl0 = wr * 64 + m * 16 + q * 4;
#pragma unroll
            for (int e = 0; e < 4; ++e) {
                int rl = rl0 + e;
                int bn = bn0 + rl;
                float sl = dis[bn]; sl *= sl;
                float mv = sl * acc[m][n][e] + gb;
                if (hasA) mv += Apart[((int64_t)t * 1024 + bn) * 128 + col];
                ushort_t rbv = *(const ushort_t*)(AsB + rl * 256 + (seg16 ^ ((rl & 7) << 4)) + wb);
                float v = fmaxf(mv * sc + bb, 0.f) + bf2f(rbv);
                Hout[(row0 + rl) * 128 + col] = f2bf(v);
            }
        }
    }
}

// ---------------- fused LSTM step: gates GEMM (dual source) + cell, two layers per dispatch.
// Blocks 0..127: layer A (step t); blocks 128..255: layer B (step t-1).
// Each wave: 16 rows x 512 cols -> holds i,f,g,o for its rows in-register.
__global__ __launch_bounds__(256) void lstm_step(
    const ushort_t* __restrict__ X1, const ushort_t* __restrict__ Hp1,
    ushort_t* __restrict__ Ho1, float* __restrict__ C1,
    const ushort_t* __restrict__ X2, const ushort_t* __restrict__ Hp2,
    ushort_t* __restrict__ Ho2, float* __restrict__ C2,
    const ushort_t* __restrict__ Wi1, const ushort_t* __restrict__ Wh1,
    const ushort_t* __restrict__ Wi2, const ushort_t* __restrict__ Wh2,
    const float* __restrict__ bs1, const float* __restrict__ bs2) {
    __shared__ __align__(16) char As[8192];    // 64 rows x 64k bf16
    __shared__ __align__(16) char Bs[65536];   // 512 cols x 64k bf16
    const int bx = blockIdx.x;
    const ushort_t *X, *Hp, *Wi, *Wh; ushort_t* Ho; float* C; const float* bs;
    int row0;
    if (bx < 128) {
        if (!X1) return;
        X = X1; Hp = Hp1; Ho = Ho1; C = C1; Wi = Wi1; Wh = Wh1; bs = bs1; row0 = bx * 64;
    } else {
        if (!X2) return;
        X = X2; Hp = Hp2; Ho = Ho2; C = C2; Wi = Wi2; Wh = Wh2; bs = bs2; row0 = (bx - 128) * 64;
    }
    const int tid = threadIdx.x, lane = tid & 63, w = tid >> 6, q = lane >> 4, l15 = lane & 15;
    f32x4 acc[32];
#pragma unroll
    for (int n = 0; n < 32; ++n) acc[n] = f32x4{0.f, 0.f, 0.f, 0.f};
    for (int s = 0; s < 2; ++s) {
        const ushort_t* Ap = s ? Hp : X;
        const ushort_t* Wp = s ? Wh : Wi;
        for (int k0 = 0; k0 < 128; k0 += 64) {
            __syncthreads();
#pragma unroll
            for (int i = 0; i < 2; ++i) {
                int id = i * 256 + tid; int r = id >> 3, sg = id & 7;
                uint4 v = *(const uint4*)(Ap + (int64_t)(row0 + r) * 128 + k0 + sg * 8);
                *(uint4*)(As + r * 128 + ((sg * 16) ^ ((r & 7) << 4))) = v;
            }
#pragma unroll
            for (int i = 0; i < 16; ++i) {
                int id = i * 256 + tid; int r = id >> 3, sg = id & 7;
                uint4 v = *(const uint4*)(Wp + (int64_t)r * 128 + k0 + sg * 8);
                *(uint4*)(Bs + r * 128 + ((sg * 16) ^ ((r & 7) << 4))) = v;
            }
            __syncthreads();
#pragma unroll
            for (int kk = 0; kk < 2; ++kk) {
                int arow = w * 16 + l15;
                bf16x8 af = __builtin_bit_cast(bf16x8,
                    *(const uint4*)(As + arow * 128 + ((kk * 64 + q * 16) ^ ((arow & 7) << 4))));
#pragma unroll
                for (int n = 0; n < 32; ++n) {
                    int col = n * 16 + l15;
                    bf16x8 bfr = __builtin_bit_cast(bf16x8,
                        *(const uint4*)(Bs + col * 128 + ((kk * 64 + q * 16) ^ ((col & 7) << 4))));
                    acc[n] = __builtin_amdgcn_mfma_f32_16x16x32_bf16(af, bfr, acc[n], 0, 0, 0);
                }
            }
        }
    }
    // cell (each lane has i,f,g,o for its positions: n, n+8, n+16, n+24)
    const int rbase = row0 + w * 16;
#pragma unroll
    for (int n = 0; n < 8; ++n) {
        int col = n * 16 + l15;
        float bi = bs[col], bff = bs[128 + col], bg = bs[256 + col], bo = bs[384 + col];
        f32x4* cp = (f32x4*)(C + (int64_t)rbase * 128 + n * 256 + lane * 4);
        f32x4 cprev = *cp, cnew;
#pragma unroll
        for (int e = 0; e < 4; ++e) {
            float ig = sigm(acc[n][e] + bi);
            float fg = sigm(acc[n + 8][e] + bff);
            float gg = tanhf(acc[n + 16][e] + bg);
            float og = sigm(acc[n + 24][e] + bo);
            float c = fg * cprev[e] + ig * gg;
            cnew[e] = c;
            float hn = og * tanhf(c);
            Ho[(int64_t)(rbase + q * 4 + e) * 128 + col] = f2bf(hn);
        }
        *cp = cnew;
    }
}

// ---------------- output head
__global__ __launch_bounds__(64) void out_head(const ushort_t* __restrict__ y,
                                               const float* __restrict__ w1,
                                               const float* __restrict__ b1,
                                               const float* __restrict__ g,
                                               const float* __restrict__ be,
                                               const float* __restrict__ w2,
                                               const float* __restrict__ b2,
                                               float* __restrict__ out) {
    int r = blockIdx.x;  // 0..8191
    int j = threadIdx.x; // 0..63
    const ushort_t* yr = y + (int64_t)r * 128;
    float acc = b1[j];
    for (int k = 0; k < 128; ++k) acc += bf2f(yr[k]) * w1[k * 64 + j];
    float s = acc;
    for (int off = 32; off; off >>= 1) s += __shfl_xor(s, off, 64);
    float mu = s * (1.f / 64.f);
    float d = acc - mu;
    float vs = d * d;
    for (int off = 32; off; off >>= 1) vs += __shfl_xor(vs, off, 64);
    float var = vs * (1.f / 64.f);
    float z = fmaxf(d * rsqrtf(var + EPS) * g[j] + be[j], 0.f);
    float p = z * w2[j];
    for (int off = 32; off; off >>= 1) p += __shfl_xor(p, off, 64);
    if (j == 0) out[r] = p + b2[0];
}

extern "C" void kernel_launch(void* const* d_in, const int* in_sizes, int n_in,
                              void* d_out, int out_size, void* d_ws, size_t ws_size,
                              hipStream_t stream) {
    const float* x    = (const float*)d_in[0];
    const int*   eidx = (const int*)d_in[1];
    const float* ewt  = (const float*)d_in[2];
    const float* efeat= (const float*)d_in[3];
    const float* w_in = (const float*)d_in[4];
    const float* b_in = (const float*)d_in[5];
    const float* lng  = (const float*)d_in[6];
    const float* lnb  = (const float*)d_in[7];
    const float* we1  = (const float*)d_in[8];
    const float* be1  = (const float*)d_in[9];
    const float* we2  = (const float*)d_in[10];
    const float* be2  = (const float*)d_in[11];
    const float* gcnw = (const float*)d_in[12];
    const float* gcnb = (const float*)d_in[13];
    const float* bng  = (const float*)d_in[14];
    const float* bnb  = (const float*)d_in[15];
    const float* wih  = (const float*)d_in[16];
    const float* whh  = (const float*)d_in[17];
    const float* bih  = (const float*)d_in[18];
    const float* bhh  = (const float*)d_in[19];
    const float* wo1  = (const float*)d_in[20];
    const float* bo1  = (const float*)d_in[21];
    const float* lnog = (const float*)d_in[22];
    const float* lnob = (const float*)d_in[23];
    const float* wo2  = (const float*)d_in[24];
    const float* bo2  = (const float*)d_in[25];
    float* out = (float*)d_out;

    // ---- workspace layout
    char* W = (char*)d_ws;
    ushort_t* hcur_bf = (ushort_t*)(W);                        // 32MB [16][8192][128]
    ushort_t* ybf     = (ushort_t*)(W + (32ll << 20));         // 32MB layer-1 outputs
    ushort_t* hwT     = (ushort_t*)(W + (64ll << 20));         // 4MB  [16][128][1024]
    float*    Apart   = (float*)(W + (68ll << 20));            // 8MB  [16][1024][128]
    float*    Adense  = (float*)(W + (76ll << 20));            // 4MB
    ushort_t* Adense_bf = (ushort_t*)(W + (80ll << 20));       // 2MB
    float*    c1      = (float*)(W + (82ll << 20));            // 4MB
    float*    c2      = (float*)(W + (86ll << 20));            // 4MB
    ushort_t* zbuf    = (ushort_t*)(W + (90ll << 20));         // 2MB zeros
    ushort_t* h2      = (ushort_t*)(W + (92ll << 20));         // 2MB layer-2 h
    float*    ew      = (float*)(W + (94ll << 20));            // 128KB
    float*    dis     = (float*)(W + (94ll << 20) + 0x20000);  // 32KB
    float*    bsum    = (float*)(W + (94ll << 20) + 0x28000);  // 4KB [2][512]
    ushort_t* gcnwT   = (ushort_t*)(W + (94ll << 20) + 0x30000); // 128KB
    ushort_t* wih_bf  = (ushort_t*)(W + (94ll << 20) + 0x50000); // 256KB
    ushort_t* whh_bf  = (ushort_t*)(W + (94ll << 20) + 0x90000); // 256KB

    const int* srcI = eidx;
    const int* dstI = eidx + 32768;

    // graph preprocessing
    edge_att<<<128, 256, 0, stream>>>(efeat, we1, be1, we2, be2, ewt, ew);
    deg_init<<<32, 256, 0, stream>>>(dis);
    deg_acc<<<128, 256, 0, stream>>>(dstI, ew, dis);
    make_dis<<<32, 256, 0, stream>>>(dis);
    hipMemsetAsync(Adense, 0, 1048576 * sizeof(float), stream);
    scatterA<<<128, 256, 0, stream>>>(srcI, dstI, ew, dis, Adense);
    convF2B<<<4096, 256, 0, stream>>>(Adense, Adense_bf, 1048576);

    // weight conversions
    convW<<<256, 256, 0, stream>>>(gcnw, gcnwT);
    convF2B<<<512, 256, 0, stream>>>(wih, wih_bf, 131072);
    convF2B<<<512, 256, 0, stream>>>(whh, whh_bf, 131072);
    bias_sum<<<4, 256, 0, stream>>>(bih, bhh, bsum);

    // input projection (bf16 only)
    in_proj_ln<<<23552, 128, 0, stream>>>(x, w_in, b_in, lng, lnb, hcur_bf);

    // GCN layers
    for (int l = 0; l < 4; ++l) {
        gemm_feat_t<<<dim3(8, 16, 1), 256, 0, stream>>>(hcur_bf, gcnwT + l * 16384, hwT);
        gemm_adj<<<dim3(16, 1, 16), 256, 0, stream>>>(Adense_bf, hwT, Apart);
        gcn_fused<<<1024, 256, 0, stream>>>(hcur_bf, gcnwT + l * 16384, Apart, dis,
                                            gcnb + l * 128, bng + l * 128, bnb + l * 128,
                                            hcur_bf);
    }

    // LSTM: 17 dispatches; blocks 0-127 run layer1 step t, blocks 128-255 layer2 step t-1
    hipMemsetAsync(c1, 0, 1048576 * sizeof(float), stream);
    hipMemsetAsync(c2, 0, 1048576 * sizeof(float), stream);
    hipMemsetAsync(zbuf, 0, 1048576 * sizeof(ushort_t), stream);
    for (int t = 0; t <= 16; ++t) {
        const ushort_t* X1  = (t < 16) ? hcur_bf + (int64_t)t * 1048576 : nullptr;
        const ushort_t* Hp1 = (t == 0) ? zbuf : ybf + (int64_t)(t - 1) * 1048576;
        ushort_t*       Ho1 = (t < 16) ? ybf + (int64_t)t * 1048576 : nullptr;
        const ushort_t* X2  = (t >= 1) ? ybf + (int64_t)(t - 1) * 1048576 : nullptr;
        const ushort_t* Hp2 = (t == 1) ? zbuf : h2;
        lstm_step<<<256, 256, 0, stream>>>(X1, Hp1, Ho1, c1,
                                           X2, Hp2, h2, c2,
                                           wih_bf, whh_bf, wih_bf + 65536, whh_bf + 65536,
                                           bsum, bsum + 512);
    }

    // output head
    out_head<<<8192, 64, 0, stream>>>(h2, wo1, bo1, lnog, lnob, wo2, bo2, out);
}

// Round 4
// 638.101 us; speedup vs baseline: 3.3568x; 1.1936x over previous
//
#include <hip/hip_runtime.h>
#include <cstdint>

// B=8, S=16, N=1024, F=16, H=128, E=32768, L=4, BN=8192
#define EPS 1e-5f

typedef unsigned short ushort_t;
typedef __bf16 bf16x8 __attribute__((ext_vector_type(8)));
typedef float f32x4 __attribute__((ext_vector_type(4)));

__device__ __forceinline__ float sigm(float x) { return 1.f / (1.f + expf(-x)); }
__device__ __forceinline__ unsigned short f2bf(float f) {
    unsigned int u = __builtin_bit_cast(unsigned int, f);
    return (unsigned short)((u + 0x7fffu + ((u >> 16) & 1u)) >> 16);
}
__device__ __forceinline__ float bf2f(unsigned short s) {
    unsigned int u = ((unsigned int)s) << 16;
    return __builtin_bit_cast(float, u);
}

// ---------------- edge attention
__global__ __launch_bounds__(256) void edge_att(const float* __restrict__ ef,
                                                const float* __restrict__ we1,
                                                const float* __restrict__ be1,
                                                const float* __restrict__ we2,
                                                const float* __restrict__ be2,
                                                const float* __restrict__ ewin,
                                                float* __restrict__ ew) {
    int e = blockIdx.x * blockDim.x + threadIdx.x;
    if (e >= 32768) return;
    float x = ef[e];
    float acc = 0.f;
    for (int h = 0; h < 128; ++h) {
        float v = fmaxf(x * we1[h] + be1[h], 0.f);
        acc += v * we2[h];
    }
    ew[e] = ewin[e] * sigm(acc + be2[0]);
}

__global__ __launch_bounds__(256) void deg_init(float* __restrict__ deg) {
    int i = blockIdx.x * blockDim.x + threadIdx.x;
    if (i < 8192) deg[i] = 1.0f;
}
__global__ __launch_bounds__(256) void deg_acc(const int* __restrict__ dst,
                                               const float* __restrict__ ew,
                                               float* __restrict__ deg) {
    int e = blockIdx.x * blockDim.x + threadIdx.x;
    if (e < 32768) atomicAdd(&deg[dst[e]], ew[e]);
}
__global__ __launch_bounds__(256) void make_dis(float* __restrict__ deg) {
    int i = blockIdx.x * blockDim.x + threadIdx.x;
    if (i < 8192) { float d = deg[i]; deg[i] = (d > 0.f) ? rsqrtf(d) : 0.f; }
}
__global__ __launch_bounds__(256) void scatterA(const int* __restrict__ src,
                                                const int* __restrict__ dst,
                                                const float* __restrict__ ew,
                                                const float* __restrict__ dis,
                                                float* __restrict__ A) {
    int e = blockIdx.x * blockDim.x + threadIdx.x;
    if (e >= 32768) return;
    int s = src[e], d = dst[e];
    atomicAdd(&A[d * 1024 + s], dis[s] * ew[e] * dis[d]);
}

// ---------------- converters
__global__ __launch_bounds__(256) void convF2B(const float* __restrict__ s,
                                               ushort_t* __restrict__ d, int n) {
    int i = blockIdx.x * blockDim.x + threadIdx.x;
    if (i < n) d[i] = f2bf(s[i]);
}
// gcnw [l][in][out] -> gcnwT [l][out][in] bf16
__global__ __launch_bounds__(256) void convW(const float* __restrict__ w,
                                             ushort_t* __restrict__ wt) {
    int i = blockIdx.x * blockDim.x + threadIdx.x;  // 4*128*128
    if (i >= 65536) return;
    int l = i >> 14, rem = i & 16383, in = rem >> 7, out = rem & 127;
    wt[l * 16384 + out * 128 + in] = f2bf(w[i]);
}
// LSTM weights -> gate-interleaved layout: col' = hg*64 + gate*16 + hl  (h = hg*16+hl)
__global__ __launch_bounds__(256) void conv_lstm_w(const float* __restrict__ wih,
                                                   const float* __restrict__ whh,
                                                   ushort_t* __restrict__ wgi,
                                                   ushort_t* __restrict__ wgh) {
    int o = blockIdx.x * blockDim.x + threadIdx.x;  // 2*512*128
    if (o >= 131072) return;
    int l = o >> 16, rem = o & 65535, c = rem >> 7, k = rem & 127;
    int g = (c >> 4) & 3, h = (c >> 6) * 16 + (c & 15);
    int src = (l * 512 + g * 128 + h) * 128 + k;
    wgi[o] = f2bf(wih[src]);
    wgh[o] = f2bf(whh[src]);
}
__global__ __launch_bounds__(256) void conv_lstm_b(const float* __restrict__ bih,
                                                   const float* __restrict__ bhh,
                                                   float* __restrict__ bsg) {
    int o = blockIdx.x * blockDim.x + threadIdx.x;  // 1024
    if (o >= 1024) return;
    int l = o >> 9, c = o & 511;
    int g = (c >> 4) & 3, h = (c >> 6) * 16 + (c & 15);
    int src = l * 512 + g * 128 + h;
    bsg[o] = bih[src] + bhh[src];
}

// ---------------- input projection + LN + ReLU -> hcur_bf only
__global__ __launch_bounds__(128) void in_proj_ln(const float* __restrict__ x,
                                                  const float* __restrict__ w,
                                                  const float* __restrict__ bias,
                                                  const float* __restrict__ g,
                                                  const float* __restrict__ be,
                                                  ushort_t* __restrict__ hb) {
    int r = blockIdx.x;            // k*1024 + n, k in [0,23)
    int h = threadIdx.x;
    int k = r >> 10, n = r & 1023;
    __shared__ float xs[16];
    __shared__ float red[128];
    if (h < 16) xs[h] = x[(int64_t)r * 16 + h];
    __syncthreads();
    float acc = bias[h];
#pragma unroll
    for (int f = 0; f < 16; ++f) acc += xs[f] * w[f * 128 + h];
    red[h] = acc; __syncthreads();
    for (int off = 64; off; off >>= 1) { if (h < off) red[h] += red[h + off]; __syncthreads(); }
    float mu = red[0] * (1.f / 128.f); __syncthreads();
    float d = acc - mu; red[h] = d * d; __syncthreads();
    for (int off = 64; off; off >>= 1) { if (h < off) red[h] += red[h + off]; __syncthreads(); }
    float var = red[0] * (1.f / 128.f);
    float v = fmaxf(d * rsqrtf(var + EPS) * g[h] + be[h], 0.f);
    ushort_t vb = f2bf(v);
#pragma unroll
    for (int b = 0; b < 8; ++b) {
        int t = k - b;
        if (t >= 0 && t < 16)
            hb[((int64_t)t * 8192 + b * 1024 + n) * 128 + h] = vb;
    }
}

// ---------------- feature GEMM for rows<1024 per t, transposed output hwT[t][col][bn]
__global__ __launch_bounds__(256) void gemm_feat_t(const ushort_t* __restrict__ Hin,
                                                   const ushort_t* __restrict__ Wt,
                                                   ushort_t* __restrict__ hwT) {
    __shared__ __align__(16) char AsB[32768];
    __shared__ __align__(16) char BsB[32768];
    const int tid = threadIdx.x, lane = tid & 63, wid = tid >> 6;
    const int wr = wid >> 1, wc = wid & 1, q = lane >> 4, l15 = lane & 15;
    const int t = blockIdx.y;
    const int row0 = blockIdx.x * 128;
    const ushort_t* Ap = Hin + (int64_t)t * 1048576 + (int64_t)row0 * 128;
    f32x4 acc[4][4];
#pragma unroll
    for (int m = 0; m < 4; ++m)
#pragma unroll
        for (int n = 0; n < 4; ++n) acc[m][n] = f32x4{0.f, 0.f, 0.f, 0.f};
#pragma unroll
    for (int i = 0; i < 8; ++i) {
        int id = i * 256 + tid; int r = id >> 4, sg = id & 15;
        uint4 va = *(const uint4*)(Ap + r * 128 + sg * 8);
        *(uint4*)(AsB + r * 256 + ((sg * 16) ^ ((r & 7) << 4))) = va;
        uint4 vb = *(const uint4*)(Wt + r * 128 + sg * 8);
        *(uint4*)(BsB + r * 256 + ((sg * 16) ^ ((r & 7) << 4))) = vb;
    }
    __syncthreads();
#pragma unroll
    for (int kk = 0; kk < 4; ++kk) {
        bf16x8 af[4], bfr[4];
#pragma unroll
        for (int m = 0; m < 4; ++m) {
            int row = wr * 64 + m * 16 + l15;
            af[m] = __builtin_bit_cast(bf16x8,
                *(const uint4*)(AsB + row * 256 + ((kk * 64 + q * 16) ^ ((row & 7) << 4))));
        }
#pragma unroll
        for (int n = 0; n < 4; ++n) {
            int col = wc * 64 + n * 16 + l15;
            bfr[n] = __builtin_bit_cast(bf16x8,
                *(const uint4*)(BsB + col * 256 + ((kk * 64 + q * 16) ^ ((col & 7) << 4))));
        }
#pragma unroll
        for (int m = 0; m < 4; ++m)
#pragma unroll
            for (int n = 0; n < 4; ++n)
                acc[m][n] = __builtin_amdgcn_mfma_f32_16x16x32_bf16(af[m], bfr[n], acc[m][n], 0, 0, 0);
    }
#pragma unroll
    for (int m = 0; m < 4; ++m) {
        int bn = row0 + wr * 64 + m * 16 + q * 4;
#pragma unroll
        for (int n = 0; n < 4; ++n) {
            int col = wc * 64 + n * 16 + l15;
            ushort4 u;
            u.x = f2bf(acc[m][n][0]); u.y = f2bf(acc[m][n][1]);
            u.z = f2bf(acc[m][n][2]); u.w = f2bf(acc[m][n][3]);
            *(ushort4*)(hwT + ((int64_t)t * 128 + col) * 1024 + bn) = u;
        }
    }
}

// ---------------- adjacency GEMM: Apart[t] = Adense_bf @ hw[t]  (B as hwT [col][bn])
__global__ __launch_bounds__(256) void gemm_adj(const ushort_t* __restrict__ Abf,
                                                const ushort_t* __restrict__ hwT,
                                                float* __restrict__ Apart) {
    __shared__ __align__(16) char AsB[8192];    // 64 rows x 64k
    __shared__ __align__(16) char BsB[16384];   // 128 cols x 64k
    const int tid = threadIdx.x, lane = tid & 63, wid = tid >> 6;
    const int wr = wid >> 1, wc = wid & 1, q = lane >> 4, l15 = lane & 15;
    const int row0 = blockIdx.x * 64;
    const int t = blockIdx.z;
    const ushort_t* Bp = hwT + (int64_t)t * 131072;
    f32x4 acc[2][4];
#pragma unroll
    for (int m = 0; m < 2; ++m)
#pragma unroll
        for (int n = 0; n < 4; ++n) acc[m][n] = f32x4{0.f, 0.f, 0.f, 0.f};
    for (int k0 = 0; k0 < 1024; k0 += 64) {
        __syncthreads();
#pragma unroll
        for (int i = 0; i < 2; ++i) {
            int id = i * 256 + tid; int r = id >> 3, sg = id & 7;
            uint4 v = *(const uint4*)(Abf + (int64_t)(row0 + r) * 1024 + k0 + sg * 8);
            *(uint4*)(AsB + r * 128 + ((sg * 16) ^ ((r & 7) << 4))) = v;
        }
#pragma unroll
        for (int i = 0; i < 4; ++i) {
            int id = i * 256 + tid; int r = id >> 3, sg = id & 7;
            uint4 v = *(const uint4*)(Bp + (int64_t)r * 1024 + k0 + sg * 8);
            *(uint4*)(BsB + r * 128 + ((sg * 16) ^ ((r & 7) << 4))) = v;
        }
        __syncthreads();
#pragma unroll
        for (int kk = 0; kk < 2; ++kk) {
            bf16x8 af[2], bfr[4];
#pragma unroll
            for (int m = 0; m < 2; ++m) {
                int row = wr * 32 + m * 16 + l15;
                af[m] = __builtin_bit_cast(bf16x8,
                    *(const uint4*)(AsB + row * 128 + ((kk * 64 + q * 16) ^ ((row & 7) << 4))));
            }
#pragma unroll
            for (int n = 0; n < 4; ++n) {
                int col = wc * 64 + n * 16 + l15;
                bfr[n] = __builtin_bit_cast(bf16x8,
                    *(const uint4*)(BsB + col * 128 + ((kk * 64 + q * 16) ^ ((col & 7) << 4))));
            }
#pragma unroll
            for (int m = 0; m < 2; ++m)
#pragma unroll
                for (int n = 0; n < 4; ++n)
                    acc[m][n] = __builtin_amdgcn_mfma_f32_16x16x32_bf16(af[m], bfr[n], acc[m][n], 0, 0, 0);
        }
    }
#pragma unroll
    for (int m = 0; m < 2; ++m) {
        int rb = row0 + wr * 32 + m * 16 + q * 4;
#pragma unroll
        for (int n = 0; n < 4; ++n) {
            int c = wc * 64 + n * 16 + l15;
#pragma unroll
            for (int e = 0; e < 4; ++e)
                Apart[((int64_t)t * 1024 + rb + e) * 128 + c] = acc[m][n][e];
        }
    }
}

// ---------------- fused GCN layer: hw = Hin@W; h = relu((sl*hw + Apart + b)*scale + bnb) + Hin
__global__ __launch_bounds__(256) void gcn_fused(const ushort_t* __restrict__ Hin,
                                                 const ushort_t* __restrict__ Wt,
                                                 const float* __restrict__ Apart,
                                                 const float* __restrict__ dis,
                                                 const float* __restrict__ gcnb,
                                                 const float* __restrict__ bng,
                                                 const float* __restrict__ bnb,
                                                 ushort_t* __restrict__ Hout) {
    __shared__ __align__(16) char AsB[32768];
    __shared__ __align__(16) char BsB[32768];
    const int tid = threadIdx.x, lane = tid & 63, wid = tid >> 6;
    const int wr = wid >> 1, wc = wid & 1, q = lane >> 4, l15 = lane & 15;
    const int64_t row0 = (int64_t)blockIdx.x * 128;
    const ushort_t* Ap = Hin + row0 * 128;
    f32x4 acc[4][4];
#pragma unroll
    for (int m = 0; m < 4; ++m)
#pragma unroll
        for (int n = 0; n < 4; ++n) acc[m][n] = f32x4{0.f, 0.f, 0.f, 0.f};
#pragma unroll
    for (int i = 0; i < 8; ++i) {
        int id = i * 256 + tid; int r = id >> 4, sg = id & 15;
        uint4 va = *(const uint4*)(Ap + r * 128 + sg * 8);
        *(uint4*)(AsB + r * 256 + ((sg * 16) ^ ((r & 7) << 4))) = va;
        uint4 vb = *(const uint4*)(Wt + r * 128 + sg * 8);
        *(uint4*)(BsB + r * 256 + ((sg * 16) ^ ((r & 7) << 4))) = vb;
    }
    __syncthreads();
#pragma unroll
    for (int kk = 0; kk < 4; ++kk) {
        bf16x8 af[4], bfr[4];
#pragma unroll
        for (int m = 0; m < 4; ++m) {
            int row = wr * 64 + m * 16 + l15;
            af[m] = __builtin_bit_cast(bf16x8,
                *(const uint4*)(AsB + row * 256 + ((kk * 64 + q * 16) ^ ((row & 7) << 4))));
        }
#pragma unroll
        for (int n = 0; n < 4; ++n) {
            int col = wc * 64 + n * 16 + l15;
            bfr[n] = __builtin_bit_cast(bf16x8,
                *(const uint4*)(BsB + col * 256 + ((kk * 64 + q * 16) ^ ((col & 7) << 4))));
        }
#pragma unroll
        for (int m = 0; m < 4; ++m)
#pragma unroll
            for (int n = 0; n < 4; ++n)
                acc[m][n] = __builtin_amdgcn_mfma_f32_16x16x32_bf16(af[m], bfr[n], acc[m][n], 0, 0, 0);
    }
    const int bn0 = (int)(row0 & 8191);
    const int t = (int)(row0 >> 13);
    const bool hasA = bn0 < 1024;
    const float rs = rsqrtf(1.f + EPS);
#pragma unroll
    for (int n = 0; n < 4; ++n) {
        int col = wc * 64 + n * 16 + l15;
        float gb = gcnb[col], sc = bng[col] * rs, bb = bnb[col];
        int seg16 = (col >> 3) * 16, wb = (col & 7) * 2;
#pragma unroll
        for (int m = 0; m < 4; ++m) {
            int rl0 = wr * 64 + m * 16 + q * 4;
#pragma unroll
            for (int e = 0; e < 4; ++e) {
                int rl = rl0 + e;
                int bn = bn0 + rl;
                float sl = dis[bn]; sl *= sl;
                float mv = sl * acc[m][n][e] + gb;
                if (hasA) mv += Apart[((int64_t)t * 1024 + bn) * 128 + col];
                ushort_t rbv = *(const ushort_t*)(AsB + rl * 256 + (seg16 ^ ((rl & 7) << 4)) + wb);
                float v = fmaxf(mv * sc + bb, 0.f) + bf2f(rbv);
                Hout[(row0 + rl) * 128 + col] = f2bf(v);
            }
        }
    }
}

// ---------------- LSTM step, gate-interleaved weights, 4x4 fragments.
// Grid 512: blocks 0..255 layer1 (step t), 256..511 layer2 (step t-1).
// Block = 128 rows x 128 gate-cols (cb in [0,4)). Wave = 64 rows x 64 cols.
// Gate-col layout: col' = hg*64 + gate*16 + hl, hidden h = hg*16+hl.
// Each lane's n-frags 0..3 = i,f,g,o of ONE hidden unit -> fused cell, no exchange.
__global__ __launch_bounds__(256) void lstm_step(
    const ushort_t* __restrict__ X1, const ushort_t* __restrict__ Hp1,
    ushort_t* __restrict__ Ho1, float* __restrict__ C1,
    const ushort_t* __restrict__ X2, const ushort_t* __restrict__ Hp2,
    ushort_t* __restrict__ Ho2, float* __restrict__ C2,
    const ushort_t* __restrict__ Wi1, const ushort_t* __restrict__ Wh1,
    const ushort_t* __restrict__ Wi2, const ushort_t* __restrict__ Wh2,
    const float* __restrict__ bs1, const float* __restrict__ bs2) {
    __shared__ __align__(16) char As[16384];   // 128 rows x 64k bf16 (swizzled)
    __shared__ __align__(16) char Bs[16384];   // 128 cols x 64k bf16 (swizzled)
    int bx = blockIdx.x;
    const ushort_t *X, *Hp, *Wi, *Wh; ushort_t* Ho; float* C; const float* bs;
    if (bx < 256) {
        if (!X1) return;
        X = X1; Hp = Hp1; Ho = Ho1; C = C1; Wi = Wi1; Wh = Wh1; bs = bs1;
    } else {
        if (!X2) return;
        bx -= 256;
        X = X2; Hp = Hp2; Ho = Ho2; C = C2; Wi = Wi2; Wh = Wh2; bs = bs2;
    }
    const int row0 = (bx >> 2) * 128;
    const int cb = bx & 3;
    const int tid = threadIdx.x, lane = tid & 63, wid = tid >> 6;
    const int wr = wid >> 1, wc = wid & 1, q = lane >> 4, l15 = lane & 15;
    f32x4 acc[4][4];
#pragma unroll
    for (int m = 0; m < 4; ++m)
#pragma unroll
        for (int n = 0; n < 4; ++n) acc[m][n] = f32x4{0.f, 0.f, 0.f, 0.f};
    for (int s = 0; s < 2; ++s) {
        const ushort_t* Ap = s ? Hp : X;
        const ushort_t* Wp = (s ? Wh : Wi) + cb * 128 * 128;   // [128 cols'][128 k] slice
        for (int k0 = 0; k0 < 128; k0 += 64) {
            __syncthreads();
#pragma unroll
            for (int i = 0; i < 4; ++i) {
                int id = i * 256 + tid; int r = id >> 3, sg = id & 7;
                uint4 va = *(const uint4*)(Ap + (int64_t)(row0 + r) * 128 + k0 + sg * 8);
                *(uint4*)(As + r * 128 + ((sg * 16) ^ ((r & 7) << 4))) = va;
                uint4 vb = *(const uint4*)(Wp + r * 128 + k0 + sg * 8);
                *(uint4*)(Bs + r * 128 + ((sg * 16) ^ ((r & 7) << 4))) = vb;
            }
            __syncthreads();
#pragma unroll
            for (int kk = 0; kk < 2; ++kk) {
                bf16x8 af[4], bfr[4];
#pragma unroll
                for (int m = 0; m < 4; ++m) {
                    int row = wr * 64 + m * 16 + l15;
                    af[m] = __builtin_bit_cast(bf16x8,
                        *(const uint4*)(As + row * 128 + ((kk * 64 + q * 16) ^ ((row & 7) << 4))));
                }
#pragma unroll
                for (int n = 0; n < 4; ++n) {
                    int col = wc * 64 + n * 16 + l15;
                    bfr[n] = __builtin_bit_cast(bf16x8,
                        *(const uint4*)(Bs + col * 128 + ((kk * 64 + q * 16) ^ ((col & 7) << 4))));
                }
#pragma unroll
                for (int m = 0; m < 4; ++m)
#pragma unroll
                    for (int n = 0; n < 4; ++n)
                        acc[m][n] = __builtin_amdgcn_mfma_f32_16x16x32_bf16(af[m], bfr[n], acc[m][n], 0, 0, 0);
            }
        }
    }
    // fused cell: n = gate (i,f,g,o), hidden h = cb*32 + wc*16 + l15
    const int hidx = cb * 32 + wc * 16 + l15;
    const int cbase = cb * 128 + wc * 64 + l15;
    const float bi = bs[cbase], bff = bs[cbase + 16], bg = bs[cbase + 32], bo = bs[cbase + 48];
#pragma unroll
    for (int m = 0; m < 4; ++m) {
        int rb = row0 + wr * 64 + m * 16 + q * 4;
#pragma unroll
        for (int e = 0; e < 4; ++e) {
            int row = rb + e;
            float ig = sigm(acc[m][0][e] + bi);
            float fg = sigm(acc[m][1][e] + bff);
            float gg = tanhf(acc[m][2][e] + bg);
            float og = sigm(acc[m][3][e] + bo);
            float cprev = C[(int64_t)row * 128 + hidx];
            float c = fg * cprev + ig * gg;
            C[(int64_t)row * 128 + hidx] = c;
            Ho[(int64_t)row * 128 + hidx] = f2bf(og * tanhf(c));
        }
    }
}

// ---------------- output head
__global__ __launch_bounds__(64) void out_head(const ushort_t* __restrict__ y,
                                               const float* __restrict__ w1,
                                               const float* __restrict__ b1,
                                               const float* __restrict__ g,
                                               const float* __restrict__ be,
                                               const float* __restrict__ w2,
                                               const float* __restrict__ b2,
                                               float* __restrict__ out) {
    int r = blockIdx.x;  // 0..8191
    int j = threadIdx.x; // 0..63
    const ushort_t* yr = y + (int64_t)r * 128;
    float acc = b1[j];
    for (int k = 0; k < 128; ++k) acc += bf2f(yr[k]) * w1[k * 64 + j];
    float s = acc;
    for (int off = 32; off; off >>= 1) s += __shfl_xor(s, off, 64);
    float mu = s * (1.f / 64.f);
    float d = acc - mu;
    float vs = d * d;
    for (int off = 32; off; off >>= 1) vs += __shfl_xor(vs, off, 64);
    float var = vs * (1.f / 64.f);
    float z = fmaxf(d * rsqrtf(var + EPS) * g[j] + be[j], 0.f);
    float p = z * w2[j];
    for (int off = 32; off; off >>= 1) p += __shfl_xor(p, off, 64);
    if (j == 0) out[r] = p + b2[0];
}

extern "C" void kernel_launch(void* const* d_in, const int* in_sizes, int n_in,
                              void* d_out, int out_size, void* d_ws, size_t ws_size,
                              hipStream_t stream) {
    const float* x    = (const float*)d_in[0];
    const int*   eidx = (const int*)d_in[1];
    const float* ewt  = (const float*)d_in[2];
    const float* efeat= (const float*)d_in[3];
    const float* w_in = (const float*)d_in[4];
    const float* b_in = (const float*)d_in[5];
    const float* lng  = (const float*)d_in[6];
    const float* lnb  = (const float*)d_in[7];
    const float* we1  = (const float*)d_in[8];
    const float* be1  = (const float*)d_in[9];
    const float* we2  = (const float*)d_in[10];
    const float* be2  = (const float*)d_in[11];
    const float* gcnw = (const float*)d_in[12];
    const float* gcnb = (const float*)d_in[13];
    const float* bng  = (const float*)d_in[14];
    const float* bnb  = (const float*)d_in[15];
    const float* wih  = (const float*)d_in[16];
    const float* whh  = (const float*)d_in[17];
    const float* bih  = (const float*)d_in[18];
    const float* bhh  = (const float*)d_in[19];
    const float* wo1  = (const float*)d_in[20];
    const float* bo1  = (const float*)d_in[21];
    const float* lnog = (const float*)d_in[22];
    const float* lnob = (const float*)d_in[23];
    const float* wo2  = (const float*)d_in[24];
    const float* bo2  = (const float*)d_in[25];
    float* out = (float*)d_out;

    // ---- workspace layout (~97MB)
    char* W = (char*)d_ws;
    ushort_t* hcur_bf   = (ushort_t*)(W);                        // 32MB [16][8192][128]
    ushort_t* ybf       = (ushort_t*)(W + (32ll << 20));         // 32MB layer-1 outputs
    ushort_t* hwT       = (ushort_t*)(W + (64ll << 20));         // 4MB  [16][128][1024]
    float*    Apart     = (float*)(W + (68ll << 20));            // 8MB  [16][1024][128]
    float*    Adense    = (float*)(W + (76ll << 20));            // 4MB
    ushort_t* Adense_bf = (ushort_t*)(W + (80ll << 20));         // 2MB
    float*    c1        = (float*)(W + (82ll << 20));            // 4MB
    float*    c2        = (float*)(W + (86ll << 20));            // 4MB
    ushort_t* zbuf      = (ushort_t*)(W + (90ll << 20));         // 2MB zeros
    ushort_t* h2a       = (ushort_t*)(W + (92ll << 20));         // 2MB layer-2 h ping
    ushort_t* h2b       = (ushort_t*)(W + (94ll << 20));         // 2MB layer-2 h pong
    float*    ew        = (float*)(W + (96ll << 20));            // 128KB
    float*    dis       = (float*)(W + (96ll << 20) + 0x20000);  // 32KB
    float*    bsg       = (float*)(W + (96ll << 20) + 0x28000);  // 4KB [2][512] gate-interleaved
    ushort_t* gcnwT     = (ushort_t*)(W + (96ll << 20) + 0x30000); // 128KB
    ushort_t* wgi       = (ushort_t*)(W + (96ll << 20) + 0x50000); // 256KB [2][512][128]
    ushort_t* wgh       = (ushort_t*)(W + (96ll << 20) + 0x90000); // 256KB

    const int* srcI = eidx;
    const int* dstI = eidx + 32768;

    // graph preprocessing
    edge_att<<<128, 256, 0, stream>>>(efeat, we1, be1, we2, be2, ewt, ew);
    deg_init<<<32, 256, 0, stream>>>(dis);
    deg_acc<<<128, 256, 0, stream>>>(dstI, ew, dis);
    make_dis<<<32, 256, 0, stream>>>(dis);
    hipMemsetAsync(Adense, 0, 1048576 * sizeof(float), stream);
    scatterA<<<128, 256, 0, stream>>>(srcI, dstI, ew, dis, Adense);
    convF2B<<<4096, 256, 0, stream>>>(Adense, Adense_bf, 1048576);

    // weight conversions
    convW<<<256, 256, 0, stream>>>(gcnw, gcnwT);
    conv_lstm_w<<<512, 256, 0, stream>>>(wih, whh, wgi, wgh);
    conv_lstm_b<<<4, 256, 0, stream>>>(bih, bhh, bsg);

    // input projection (bf16 only)
    in_proj_ln<<<23552, 128, 0, stream>>>(x, w_in, b_in, lng, lnb, hcur_bf);

    // GCN layers
    for (int l = 0; l < 4; ++l) {
        gemm_feat_t<<<dim3(8, 16, 1), 256, 0, stream>>>(hcur_bf, gcnwT + l * 16384, hwT);
        gemm_adj<<<dim3(16, 1, 16), 256, 0, stream>>>(Adense_bf, hwT, Apart);
        gcn_fused<<<1024, 256, 0, stream>>>(hcur_bf, gcnwT + l * 16384, Apart, dis,
                                            gcnb + l * 128, bng + l * 128, bnb + l * 128,
                                            hcur_bf);
    }

    // LSTM: 17 dispatches; blocks 0-255 layer1 step t, 256-511 layer2 step t-1.
    hipMemsetAsync(c1, 0, 1048576 * sizeof(float), stream);
    hipMemsetAsync(c2, 0, 1048576 * sizeof(float), stream);
    hipMemsetAsync(zbuf, 0, 1048576 * sizeof(ushort_t), stream);
    for (int t = 0; t <= 16; ++t) {
        const ushort_t* X1  = (t < 16) ? hcur_bf + (int64_t)t * 1048576 : nullptr;
        const ushort_t* Hp1 = (t == 0) ? zbuf : ybf + (int64_t)(t - 1) * 1048576;
        ushort_t*       Ho1 = (t < 16) ? ybf + (int64_t)t * 1048576 : nullptr;
        const ushort_t* X2  = (t >= 1) ? ybf + (int64_t)(t - 1) * 1048576 : nullptr;
        int s2 = t - 1;  // layer-2 step index
        const ushort_t* Hp2 = (s2 <= 0) ? zbuf : (((s2 - 1) & 1) ? h2b : h2a);
        ushort_t*       Ho2 = (s2 >= 0) ? (((s2 & 1) ? h2b : h2a)) : nullptr;
        lstm_step<<<512, 256, 0, stream>>>(X1, Hp1, Ho1, c1,
                                           X2, Hp2, Ho2, c2,
                                           wgi, wgh, wgi + 65536, wgh + 65536,
                                           bsg, bsg + 512);
    }

    // output head (final layer-2 h = step 15 -> h2b)
    out_head<<<8192, 64, 0, stream>>>(h2b, wo1, bo1, lnog, lnob, wo2, bo2, out);
}